// Round 1
// baseline (711.564 us; speedup 1.0000x reference)
//
#include <hip/hip_runtime.h>
#include <math.h>

#define NB 64
#define CIN 512
#define HW 4096
#define HIDE 128
#define OP 512

// ---------------- Kernel 1: global average pool ----------------
// x: [B, CIN, H, W] fp32, each (b,c) row = 4096 contiguous floats.
// One wave (64 lanes) per row: 16 x float4 per lane, coalesced.
__global__ __launch_bounds__(256) void pool_kernel(const float* __restrict__ x,
                                                   float* __restrict__ y0) {
    const int gwave = (blockIdx.x * blockDim.x + threadIdx.x) >> 6; // row id
    const int lane  = threadIdx.x & 63;
    if (gwave >= NB * CIN) return;

    const float4* __restrict__ p = (const float4*)(x + (size_t)gwave * HW);
    float s = 0.0f;
#pragma unroll
    for (int j = 0; j < 16; ++j) {
        float4 v = p[j * 64 + lane];
        s += (v.x + v.y) + (v.z + v.w);
    }
#pragma unroll
    for (int off = 32; off >= 1; off >>= 1)
        s += __shfl_down(s, off, 64);
    if (lane == 0) y0[gwave] = s * (1.0f / (float)HW);
}

// ---------------- Kernel 2: fused tiny MLP ----------------
// One block per batch element b. 256 threads.
//   y1[h]  = sum_c y0[c] * W1[h*CIN+c]              (h < 128)
//   A1     = softmax(w2 * y1)
//   y2[k]  = y1[k]*A1[k] + sum_h y1[h]*A2[h*128+k]
//   y3[k]  = relu(w3 * y2[k])
//   out[o] = sigmoid(sum_h y3[h] * W4[o*128+h])     (o < 512)
__global__ __launch_bounds__(256) void mlp_kernel(const float* __restrict__ y0,
                                                  const float* __restrict__ W1,
                                                  const float* __restrict__ A2,
                                                  const float* __restrict__ w2p,
                                                  const float* __restrict__ w3p,
                                                  const float* __restrict__ W4,
                                                  float* __restrict__ out) {
    __shared__ float s_y0[CIN];
    __shared__ float s_y1[HIDE];
    __shared__ float s_y3[HIDE];
    __shared__ float s_red[4]; // [0:2] max partials, [2:4] sum partials

    const int b = blockIdx.x;
    const int t = threadIdx.x;

    // stage y0 row
    s_y0[t]       = y0[b * CIN + t];
    s_y0[t + 256] = y0[b * CIN + t + 256];
    __syncthreads();

    const float w2 = *w2p;
    const float w3 = *w3p;

    // y1 = W1 @ y0
    if (t < HIDE) {
        const float* __restrict__ wr = W1 + t * CIN;
        float acc = 0.0f;
#pragma unroll 8
        for (int c = 0; c < CIN; ++c) acc += s_y0[c] * wr[c];
        s_y1[t] = acc;
    }
    __syncthreads();

    // softmax over 128 values of w2*y1 (threads 0..127 = waves 0,1)
    float v = (t < HIDE) ? w2 * s_y1[t] : -INFINITY;
    float m = v;
#pragma unroll
    for (int off = 32; off >= 1; off >>= 1)
        m = fmaxf(m, __shfl_down(m, off, 64));
    if ((t & 63) == 0 && t < HIDE) s_red[t >> 6] = m;
    __syncthreads();
    const float M = fmaxf(s_red[0], s_red[1]);

    float e = (t < HIDE) ? expf(v - M) : 0.0f;
    float ssum = e;
#pragma unroll
    for (int off = 32; off >= 1; off >>= 1)
        ssum += __shfl_down(ssum, off, 64);
    if ((t & 63) == 0 && t < HIDE) s_red[2 + (t >> 6)] = ssum;
    __syncthreads();
    const float S = s_red[2] + s_red[3];

    // y2 / relu
    if (t < HIDE) {
        const float a1  = e / S;
        float acc = s_y1[t] * a1;
#pragma unroll 8
        for (int h = 0; h < HIDE; ++h) acc += s_y1[h] * A2[h * HIDE + t];
        s_y3[t] = fmaxf(w3 * acc, 0.0f);
    }
    __syncthreads();

    // out = sigmoid(W4 @ y3): each thread does 2 outputs
#pragma unroll
    for (int rep = 0; rep < 2; ++rep) {
        const int o = t + rep * 256;
        const float* __restrict__ wr = W4 + o * HIDE;
        float acc = 0.0f;
#pragma unroll 8
        for (int h = 0; h < HIDE; ++h) acc += s_y3[h] * wr[h];
        out[b * OP + o] = 1.0f / (1.0f + expf(-acc));
    }
}

extern "C" void kernel_launch(void* const* d_in, const int* in_sizes, int n_in,
                              void* d_out, int out_size, void* d_ws, size_t ws_size,
                              hipStream_t stream) {
    const float* x  = (const float*)d_in[0];
    const float* W1 = (const float*)d_in[1];
    const float* A2 = (const float*)d_in[2];
    const float* w2 = (const float*)d_in[3];
    const float* w3 = (const float*)d_in[4];
    const float* W4 = (const float*)d_in[5];
    float* out = (float*)d_out;
    float* y0  = (float*)d_ws; // 64*512 floats = 128 KiB

    // pool: one wave per (b,c) row -> 32768 waves -> 8192 blocks of 256
    pool_kernel<<<(NB * CIN) / 4, 256, 0, stream>>>(x, y0);
    // fused MLP: one block per batch element
    mlp_kernel<<<NB, 256, 0, stream>>>(y0, W1, A2, w2, w3, W4, out);
}